// Round 7
// baseline (228.529 us; speedup 1.0000x reference)
//
#include <hip/hip_runtime.h>
#include <math.h>

#define D 256

__device__ __forceinline__ float wave_reduce_sum(float v) {
#pragma unroll
    for (int off = 32; off > 0; off >>= 1) v += __shfl_xor(v, off);
    return v;
}
__device__ __forceinline__ float wave_reduce_max(float v) {
#pragma unroll
    for (int off = 32; off > 0; off >>= 1) v = fmaxf(v, __shfl_xor(v, off));
    return v;
}

__device__ __forceinline__ float4 load_row_f32(const float* __restrict__ E_w,
                                               int idx, int lane) {
    return ((const float4*)(E_w + (size_t)idx * D))[lane];
}
__device__ __forceinline__ float4 load_row_i8(const signed char* __restrict__ Eq,
                                              const float* __restrict__ scales,
                                              int idx, int lane) {
    const char4 c = ((const char4*)(Eq + (size_t)idx * D))[lane];  // 256B row
    const float f = scales[idx];                    // wave-uniform -> s_load
    return make_float4(f * (float)c.x, f * (float)c.y,
                       f * (float)c.z, f * (float)c.w);
}
template <bool I8>
__device__ __forceinline__ float4 load_row(const float* __restrict__ E_w,
                                           const signed char* __restrict__ Eq,
                                           const float* __restrict__ scales,
                                           int idx, int lane) {
    return I8 ? load_row_i8(Eq, scales, idx, lane) : load_row_f32(E_w, idx, lane);
}

// ---------------------------------------------------------------------------
// K0: E_w fp32 -> int8 + per-row scale. Wave-per-row, 4 rows in flight.
// Pure cold-HBM stream: 102 MB read + 26 MB write ~ 20-25 us.
// ---------------------------------------------------------------------------
__global__ __launch_bounds__(256) void convert_i8_kernel(
    const float* __restrict__ E_w, signed char* __restrict__ Eq,
    float* __restrict__ scales, int n_vocab) {
    const int lane = threadIdx.x & 63;
    const int gw   = (blockIdx.x * 256 + threadIdx.x) >> 6;  // global wave id
    const int nw   = (gridDim.x * 256) >> 6;

    for (int r0 = gw * 4; r0 < n_vocab; r0 += nw * 4) {
        const int n = min(4, n_vocab - r0);
        float4 v[4];
#pragma unroll
        for (int k = 0; k < 4; ++k)
            if (k < n) v[k] = load_row_f32(E_w, r0 + k, lane);
#pragma unroll
        for (int k = 0; k < 4; ++k) {
            if (k >= n) break;
            float mx = fmaxf(fmaxf(fabsf(v[k].x), fabsf(v[k].y)),
                             fmaxf(fabsf(v[k].z), fabsf(v[k].w)));
            mx = wave_reduce_max(mx);
            const float inv = (mx > 0.f) ? 127.f / mx : 0.f;
            const int qx = __float2int_rn(v[k].x * inv);
            const int qy = __float2int_rn(v[k].y * inv);
            const int qz = __float2int_rn(v[k].z * inv);
            const int qw = __float2int_rn(v[k].w * inv);
            const unsigned int packed =
                ((unsigned int)(unsigned char)(signed char)qx) |
                ((unsigned int)(unsigned char)(signed char)qy << 8) |
                ((unsigned int)(unsigned char)(signed char)qz << 16) |
                ((unsigned int)(unsigned char)(signed char)qw << 24);
            ((unsigned int*)(Eq + (size_t)(r0 + k) * D))[lane] = packed;
            if (lane == 0) scales[r0 + k] = mx * (1.f / 127.f);
        }
    }
}

// ---------------------------------------------------------------------------
// K1: blocks [0, nbneg)          -> negs, wave-per-(b,m), 4 bm per block
//     blocks [nbneg, nbneg + B)  -> main path for batch row b
// Negs first: they're the long pole, earlier dispatch = better tail.
// Negs waves are barrier-free with a depth-10 load pipeline (10 rows of
// 256B int8 + 10 scalar scales in flight per wave).
// ---------------------------------------------------------------------------
template <bool I8>
__global__ __launch_bounds__(256) void abae_fused_kernel(
    const int* __restrict__ pos, const int* __restrict__ negs,
    const float* __restrict__ E_w, const signed char* __restrict__ Eq,
    const float* __restrict__ scales, const float* __restrict__ T_w,
    const float* __restrict__ M_w, const float* __restrict__ M_b,
    const float* __restrict__ lin_w, const float* __restrict__ lin_b,
    float* __restrict__ r_s, float* __restrict__ z_s, float* __restrict__ z_n,
    int B, int BM, int nbneg, int L, int n_asp) {
    const int t    = threadIdx.x;
    const int lane = t & 63;
    const int wv   = t >> 6;            // 0..3

    __shared__ float4 sred[4][64];
    __shared__ float  sy[D];            // y_s, later z_s
    __shared__ float  smy[D];           // My
    __shared__ float  slog[16];
    __shared__ float  sp[16];
    __shared__ float  sscal[4];

    if (blockIdx.x < (unsigned)nbneg) {
        // ========== negs path: wave-per-bm, no barriers =====================
        const int bm = blockIdx.x * 4 + wv;
        if (bm < BM) {
            const int* __restrict__ idxp = negs + (size_t)bm * L;
            float4 acc = make_float4(0.f, 0.f, 0.f, 0.f);
            int l = 0;
            for (; l + 10 <= L; l += 10) {      // depth-10 pipeline
                int id[10];
#pragma unroll
                for (int k = 0; k < 10; ++k) id[k] = idxp[l + k];
                float4 v[10];
#pragma unroll
                for (int k = 0; k < 10; ++k)
                    v[k] = load_row<I8>(E_w, Eq, scales, id[k], lane);
#pragma unroll
                for (int k = 0; k < 10; ++k) {
                    acc.x += v[k].x; acc.y += v[k].y;
                    acc.z += v[k].z; acc.w += v[k].w;
                }
            }
            for (; l < L; ++l) {
                const float4 v = load_row<I8>(E_w, Eq, scales, idxp[l], lane);
                acc.x += v.x; acc.y += v.y; acc.z += v.z; acc.w += v.w;
            }
            const float invL = 1.f / (float)L;
            acc.x *= invL; acc.y *= invL; acc.z *= invL; acc.w *= invL;
            float ss = acc.x * acc.x + acc.y * acc.y + acc.z * acc.z + acc.w * acc.w;
            ss = wave_reduce_sum(ss);
            const float inv = 1.f / fmaxf(sqrtf(ss), 1e-12f);
            acc.x *= inv; acc.y *= inv; acc.z *= inv; acc.w *= inv;
            ((float4*)(z_n + (size_t)bm * D))[lane] = acc;
        }
        return;
    }

    // ==================== main path: batch row b ============================
    const int b = blockIdx.x - nbneg;
    const int* __restrict__ posb = pos + (size_t)b * L;
    const int C  = (L + 3) / 4;         // 25 tokens per wave
    const int s0 = wv * C;
    const int e0 = min(L, s0 + C);

    // ---- phase 1: y_s = mean_l E[pos[b,l]], 5 gathers in flight ----
    float4 acc = make_float4(0.f, 0.f, 0.f, 0.f);
    int l = s0;
    for (; l + 5 <= e0; l += 5) {
        const int i0 = posb[l], i1 = posb[l + 1], i2 = posb[l + 2],
                  i3 = posb[l + 3], i4 = posb[l + 4];
        const float4 v0 = load_row<I8>(E_w, Eq, scales, i0, lane);
        const float4 v1 = load_row<I8>(E_w, Eq, scales, i1, lane);
        const float4 v2 = load_row<I8>(E_w, Eq, scales, i2, lane);
        const float4 v3 = load_row<I8>(E_w, Eq, scales, i3, lane);
        const float4 v4 = load_row<I8>(E_w, Eq, scales, i4, lane);
        acc.x += v0.x + v1.x + v2.x + v3.x + v4.x;
        acc.y += v0.y + v1.y + v2.y + v3.y + v4.y;
        acc.z += v0.z + v1.z + v2.z + v3.z + v4.z;
        acc.w += v0.w + v1.w + v2.w + v3.w + v4.w;
    }
    for (; l < e0; ++l) {
        const float4 v = load_row<I8>(E_w, Eq, scales, posb[l], lane);
        acc.x += v.x; acc.y += v.y; acc.z += v.z; acc.w += v.w;
    }
    sred[wv][lane] = acc;
    __syncthreads();
    if (wv == 0) {
        float4 y  = sred[0][lane];
        const float4 a1 = sred[1][lane], a2 = sred[2][lane], a3 = sred[3][lane];
        const float invL = 1.f / (float)L;
        y.x = (y.x + a1.x + a2.x + a3.x) * invL;
        y.y = (y.y + a1.y + a2.y + a3.y) * invL;
        y.z = (y.z + a1.z + a2.z + a3.z) * invL;
        y.w = (y.w + a1.w + a2.w + a3.w) * invL;
        ((float4*)sy)[lane] = y;
    }
    __syncthreads();

    // ---- phase 2: My[r] = M_b[r] + M_w[r,:] . y_s — wave-per-row, 4 rows
    // in flight (M_w fp32, L2-resident).
    {
        const float4 y4 = ((const float4*)sy)[lane];
        for (int r0 = wv * 64; r0 < wv * 64 + 64; r0 += 4) {
            const float4 m0 = ((const float4*)(M_w + (size_t)(r0 + 0) * D))[lane];
            const float4 m1 = ((const float4*)(M_w + (size_t)(r0 + 1) * D))[lane];
            const float4 m2 = ((const float4*)(M_w + (size_t)(r0 + 2) * D))[lane];
            const float4 m3 = ((const float4*)(M_w + (size_t)(r0 + 3) * D))[lane];
            float p0 = m0.x * y4.x + m0.y * y4.y + m0.z * y4.z + m0.w * y4.w;
            float p1 = m1.x * y4.x + m1.y * y4.y + m1.z * y4.z + m1.w * y4.w;
            float p2 = m2.x * y4.x + m2.y * y4.y + m2.z * y4.z + m2.w * y4.w;
            float p3 = m3.x * y4.x + m3.y * y4.y + m3.z * y4.z + m3.w * y4.w;
#pragma unroll
            for (int off = 32; off > 0; off >>= 1) {
                p0 += __shfl_xor(p0, off);
                p1 += __shfl_xor(p1, off);
                p2 += __shfl_xor(p2, off);
                p3 += __shfl_xor(p3, off);
            }
            if (lane == 0) {
                smy[r0 + 0] = p0 + M_b[r0 + 0];
                smy[r0 + 1] = p1 + M_b[r0 + 1];
                smy[r0 + 2] = p2 + M_b[r0 + 2];
                smy[r0 + 3] = p3 + M_b[r0 + 3];
            }
        }
    }
    __syncthreads();

    // ---- phase 3: z = sum_l e_l * exp(tanh(e_l . My)); rows L1-warm from
    // phase 1 (100 x 256B = 25.6 KB < 32 KB L1).
    const float4 my4 = ((const float4*)smy)[lane];
    float4 zacc = make_float4(0.f, 0.f, 0.f, 0.f);
    l = s0;
    for (; l + 1 < e0; l += 2) {
        const float4 ea = load_row<I8>(E_w, Eq, scales, posb[l], lane);
        const float4 eb = load_row<I8>(E_w, Eq, scales, posb[l + 1], lane);
        float pa = ea.x * my4.x + ea.y * my4.y + ea.z * my4.z + ea.w * my4.w;
        float pb = eb.x * my4.x + eb.y * my4.y + eb.z * my4.z + eb.w * my4.w;
#pragma unroll
        for (int off = 32; off > 0; off >>= 1) {
            pa += __shfl_xor(pa, off);
            pb += __shfl_xor(pb, off);
        }
        const float wa = expf(tanhf(pa));
        const float wb = expf(tanhf(pb));
        zacc.x += ea.x * wa + eb.x * wb;
        zacc.y += ea.y * wa + eb.y * wb;
        zacc.z += ea.z * wa + eb.z * wb;
        zacc.w += ea.w * wa + eb.w * wb;
    }
    for (; l < e0; ++l) {
        const float4 ea = load_row<I8>(E_w, Eq, scales, posb[l], lane);
        float pa = ea.x * my4.x + ea.y * my4.y + ea.z * my4.z + ea.w * my4.w;
        pa = wave_reduce_sum(pa);
        const float wa = expf(tanhf(pa));
        zacc.x += ea.x * wa; zacc.y += ea.y * wa;
        zacc.z += ea.z * wa; zacc.w += ea.w * wa;
    }
    sred[wv][lane] = zacc;
    __syncthreads();
    if (wv == 0) {
        float4 z  = sred[0][lane];
        const float4 a1 = sred[1][lane], a2 = sred[2][lane], a3 = sred[3][lane];
        z.x += a1.x + a2.x + a3.x;
        z.y += a1.y + a2.y + a3.y;
        z.z += a1.z + a2.z + a3.z;
        z.w += a1.w + a2.w + a3.w;
        float ss = z.x * z.x + z.y * z.y + z.z * z.z + z.w * z.w;
        ss = wave_reduce_sum(ss);
        const float inv = 1.f / fmaxf(sqrtf(ss), 1e-12f);
        z.x *= inv; z.y *= inv; z.z *= inv; z.w *= inv;
        ((float4*)(z_s + (size_t)b * D))[lane] = z;   // output 1: z_s
        ((float4*)sy)[lane] = z;                      // sy := z_s
    }
    __syncthreads();

    // ---- phase 4: p = softmax(z_s @ lin_w.T + lin_b) ----
    const float4 z4 = ((const float4*)sy)[lane];
    for (int a = wv; a < n_asp; a += 4) {
        const float4 w4 = ((const float4*)(lin_w + (size_t)a * D))[lane];
        float p = z4.x * w4.x + z4.y * w4.y + z4.z * w4.z + z4.w * w4.w;
        p = wave_reduce_sum(p);
        if (lane == 0) slog[a] = p + lin_b[a];
    }
    __syncthreads();
    if (t == 0) {
        float mx = -1e30f;
        for (int a = 0; a < n_asp; ++a) mx = fmaxf(mx, slog[a]);
        float s = 0.f;
        for (int a = 0; a < n_asp; ++a) {
            const float e = expf(slog[a] - mx);
            sp[a] = e; s += e;
        }
        const float invs = 1.f / s;
        for (int a = 0; a < n_asp; ++a) sp[a] *= invs;
    }
    __syncthreads();

    // ---- phase 5: r_s = l2norm(p @ T_w) ----
    float r = 0.f;
    for (int a = 0; a < n_asp; ++a) r += sp[a] * T_w[(size_t)a * D + t];
    const float sq = wave_reduce_sum(r * r);
    if (lane == 0) sscal[wv] = sq;
    __syncthreads();
    const float tot = sscal[0] + sscal[1] + sscal[2] + sscal[3];
    const float inv = 1.f / fmaxf(sqrtf(tot), 1e-12f);
    r_s[(size_t)b * D + t] = r * inv;                 // output 0: r_s
}

extern "C" void kernel_launch(void* const* d_in, const int* in_sizes, int n_in,
                              void* d_out, int out_size, void* d_ws, size_t ws_size,
                              hipStream_t stream) {
    const int*   pos   = (const int*)d_in[0];
    const int*   negs  = (const int*)d_in[1];
    const float* E_w   = (const float*)d_in[2];
    const float* T_w   = (const float*)d_in[3];
    const float* M_w   = (const float*)d_in[4];
    const float* M_b   = (const float*)d_in[5];
    const float* lin_w = (const float*)d_in[6];
    const float* lin_b = (const float*)d_in[7];
    float* out = (float*)d_out;

    const int d       = in_sizes[5];                 // 256 (M_b)
    const int n_asp   = in_sizes[7];                 // 14  (lin_b)
    const int M       = in_sizes[1] / in_sizes[0];   // 10
    const int B       = out_size / (d * (2 + M));    // 512
    const int L       = in_sizes[0] / B;             // 100
    const int n_vocab = in_sizes[2] / d;             // 100000
    (void)n_in;

    float* r_s = out;                              // [B, d]
    float* z_s = out + (size_t)B * d;              // [B, d]
    float* z_n = out + (size_t)2 * B * d;          // [B, M, d]

    const int BM    = B * M;                       // 5120
    const int nbneg = (BM + 3) / 4;                // 1280 (4 bm per block)

    const size_t need = (size_t)n_vocab * D + (size_t)n_vocab * sizeof(float);
    const bool use_i8 = ws_size >= need;

    signed char* Eq = (signed char*)d_ws;
    float* scales   = (float*)(Eq + (size_t)n_vocab * D);

    if (use_i8) {
        convert_i8_kernel<<<2048, 256, 0, stream>>>(E_w, Eq, scales, n_vocab);
        abae_fused_kernel<true><<<nbneg + B, 256, 0, stream>>>(
            pos, negs, E_w, Eq, scales, T_w, M_w, M_b, lin_w, lin_b,
            r_s, z_s, z_n, B, BM, nbneg, L, n_asp);
    } else {
        abae_fused_kernel<false><<<nbneg + B, 256, 0, stream>>>(
            pos, negs, E_w, (const signed char*)nullptr, (const float*)nullptr,
            T_w, M_w, M_b, lin_w, lin_b, r_s, z_s, z_n, B, BM, nbneg, L, n_asp);
    }
}